// Round 4
// baseline (443.071 us; speedup 1.0000x reference)
//
#include <hip/hip_runtime.h>
#include <math.h>

#define BATCH 8
#define CIN 128
#define OCH 128
#define HH 64
#define WW 64
#define HW (HH*WW)
#define NPIX (BATCH*HW)

// ---- workspace layout (float element offsets) ----
#define XT_OFF  0
#define XT_SZ   (BATCH*HW*CIN)            // x transposed to NHWC
#define WT_OFF  (XT_OFF + XT_SZ)
#define WT_SZ   (9*CIN*OCH)               // conv_w as [k][c][o]
#define WOM_OFF (WT_OFF + WT_SZ)
#define WOM_SZ  (9*CIN*28)                // off/mask weights [k][c][28]
#define PMM_OFF (WOM_OFF + WOM_SZ)
#define PMM_SZ  (NPIX*32)                 // per-pixel py[9],px[9],m[9]

// ============ kernel 1a: x NCHW -> NHWC ============
__global__ __launch_bounds__(256) void k_transpose_x(const float* __restrict__ x,
                                                     float* __restrict__ xt) {
    __shared__ float tile[32][33];
    int b   = blockIdx.z;
    int hw0 = blockIdx.x * 32;
    int c0  = blockIdx.y * 32;
    int tx = threadIdx.x, ty = threadIdx.y;
    const float* xin = x  + (size_t)b*CIN*HW;
    float*       xo  = xt + (size_t)b*HW*CIN;
    #pragma unroll
    for (int r = 0; r < 32; r += 8)
        tile[ty + r][tx] = xin[(size_t)(c0 + ty + r)*HW + hw0 + tx];
    __syncthreads();
    #pragma unroll
    for (int r = 0; r < 32; r += 8)
        xo[(size_t)(hw0 + ty + r)*CIN + c0 + tx] = tile[tx][ty + r];
}

// ============ kernel 1b: pack weights ============
__global__ __launch_bounds__(256) void k_pack_w(const float* __restrict__ conv_w,
                                                const float* __restrict__ off_w,
                                                const float* __restrict__ mask_w,
                                                float* __restrict__ wt,
                                                float* __restrict__ wom) {
    int idx = blockIdx.x * 256 + threadIdx.x;
    if (idx < 9*CIN*OCH) {
        int k = idx / (CIN*OCH);
        int rc = idx - k*(CIN*OCH);
        int c = rc / OCH;
        int o = rc - c*OCH;
        wt[idx] = conv_w[(size_t)(o*CIN + c)*9 + k];
    }
    if (idx < 9*CIN*28) {
        int k = idx / (CIN*28);
        int r2 = idx - k*(CIN*28);
        int c = r2 / 28;
        int j = r2 - c*28;
        float v = 0.f;
        if (j < 18)      v = off_w [(size_t)(j*CIN + c)*9 + k];
        else if (j < 27) v = mask_w[(size_t)((j-18)*CIN + c)*9 + k];
        wom[idx] = v;
    }
}

// ============ kernel 2: offset+mask conv -> pmm ============
// block = 512 threads = 64 px x 8 c-groups of 16ch; grid = B*H = 512.
// XCD swizzle: 512 = 8*64 -> each XCD owns one batch image (L2-resident).
__global__ __launch_bounds__(512) void k_offmask(const float* __restrict__ x,
                                                 const float* __restrict__ wom,
                                                 const float* __restrict__ off_b,
                                                 const float* __restrict__ mask_b,
                                                 float* __restrict__ pmm) {
    int bid = blockIdx.x;
    int blk = (bid & 7) * 64 + (bid >> 3);             // bijective, 512%8==0
    int b = blk >> 6;
    int h = blk & 63;
    int t = threadIdx.x;
    int p = t & 63;                                    // pixel (abs w)
    int cg = __builtin_amdgcn_readfirstlane(t >> 6);   // 0..7, wave-uniform

    float acc[27];
    #pragma unroll
    for (int j = 0; j < 27; ++j) acc[j] = 0.f;

    const float* xb = x + (size_t)b*CIN*HW + (size_t)(cg*16)*HW;
    const float* wbase = wom + (size_t)(cg*16)*28;
    for (int k = 0; k < 9; ++k) {
        int ky = k / 3, kx = k - ky*3;
        int y = h + ky - 1;
        if ((unsigned)y >= HH) continue;
        int xx = p + kx - 1;
        bool vx = (unsigned)xx < WW;
        const float* xp = xb + y*WW + xx;
        const float* wp = wbase + (size_t)k*CIN*28;    // wave-uniform -> s_load
        #pragma unroll
        for (int i = 0; i < 16; ++i) {
            float xv = vx ? xp[(size_t)i*HW] : 0.f;
            #pragma unroll
            for (int j = 0; j < 27; ++j)
                acc[j] = fmaf(xv, wp[i*28 + j], acc[j]);
        }
    }

    __shared__ float red[8][64][33];                   // +1 pad
    #pragma unroll
    for (int j = 0; j < 27; ++j) red[cg][p][j] = acc[j];
    __syncthreads();

    int rowpix = (b*HH + h)*WW;
    for (int idx = t; idx < 64*32; idx += 512) {
        int pp = idx >> 5, j = idx & 31;
        if (j >= 27) continue;
        float s = 0.f;
        #pragma unroll
        for (int g = 0; g < 8; ++g) s += red[g][pp][j];
        float outv; int slot;
        if (j < 18) {
            int kk = j >> 1;
            s += off_b[j];
            int kyy = kk / 3;
            if ((j & 1) == 0) { outv = (float)(h - 1 + kyy) + s;            slot = kk;     }
            else              { outv = (float)(pp - 1 + (kk - kyy*3)) + s;  slot = 9 + kk; }
        } else {
            s += mask_b[j - 18];
            outv = 1.f / (1.f + expf(-s));
            slot = j;
        }
        pmm[(size_t)(rowpix + pp)*32 + slot] = outv;
    }
}

// ============ kernel 3: gather + main GEMM ============
// block = 256 threads (4 waves), 32 px; grid 1024 = 4 blocks/CU (16 waves/CU).
// XCD swizzle (1024 = 8*128): each XCD owns one batch image (2.1 MiB xt slab
// -> L2-resident across all 9 k-passes; kills the 181 MB HBM re-fetch).
// T14 split gather: issue(k+1) tap loads BEFORE gemm(k) (regs in flight,
// latency hidden under ~16k-cyc gemm), finish+LDS-write after.
__global__ __launch_bounds__(256, 4) void k_main(const float* __restrict__ xt,
                                                 const float* __restrict__ wt,
                                                 const float* __restrict__ pmm,
                                                 float* __restrict__ out) {
    __shared__ float cols[2][CIN*32];                  // 32 KB

    int bid = blockIdx.x;
    int blk = (bid & 7) * 128 + (bid >> 3);            // bijective, 1024%8==0
    int b = blk >> 7;
    int r = blk & 127;
    int h = r >> 1;
    int w0 = (r & 1) << 5;
    int t = threadIdx.x;

    int og = t >> 3, pg = t & 7;      // GEMM roles: o=og*4, p=pg*4
    int gpx = t >> 3, gcg = t & 7;    // gather roles: pixel, 16-ch group

    int rowpix = (b*HH + h)*WW + w0;
    const float* xb = xt + (size_t)b*HW*CIN;
    const float* pmmp = pmm + (size_t)(rowpix + gpx)*32;

    // swizzled cols layout: (c,p) at dword c*32 + (((p>>2)^(c>>4))<<2) + (p&3)
    int wbase = gcg*16*32 + (((gpx >> 2) ^ gcg) << 2) + (gpx & 3);

    float acc[4][4];
    #pragma unroll
    for (int i = 0; i < 4; ++i)
        #pragma unroll
        for (int j = 0; j < 4; ++j) acc[i][j] = 0.f;

    // staged gather state (lives across gemm)
    float4 tv[4][4];                  // [tap][c-quarter]
    float  gw[4];
    float  gm;

    auto issue = [&](int kk) {
        float py = pmmp[kk];
        float qx = pmmp[9 + kk];
        gm       = pmmp[18 + kk];
        float fy = floorf(py), fx = floorf(qx);
        float wy = py - fy, wx = qx - fx;
        int iy = (int)fy, ix = (int)fx;
        #pragma unroll
        for (int tp = 0; tp < 4; ++tp) {
            int yy = iy + (tp >> 1), xv = ix + (tp & 1);
            bool valid = ((unsigned)yy < HH) && ((unsigned)xv < WW);
            float twt = ((tp >> 1) ? wy : 1.f - wy) * ((tp & 1) ? wx : 1.f - wx);
            gw[tp] = valid ? twt : 0.f;                // branchless OOB: w=0
            int yc = min(max(yy, 0), HH - 1);
            int xc = min(max(xv, 0), WW - 1);
            const float* src = xb + (size_t)(yc*WW + xc)*CIN + gcg*16;
            #pragma unroll
            for (int q = 0; q < 4; ++q)
                tv[tp][q] = *(const float4*)(src + q*4);
        }
    };

    auto finish = [&](int buf) {
        float* cb = &cols[buf][0] + wbase;
        #pragma unroll
        for (int q = 0; q < 4; ++q) {
            float a0 = gw[0]*tv[0][q].x + gw[1]*tv[1][q].x + gw[2]*tv[2][q].x + gw[3]*tv[3][q].x;
            float a1 = gw[0]*tv[0][q].y + gw[1]*tv[1][q].y + gw[2]*tv[2][q].y + gw[3]*tv[3][q].y;
            float a2 = gw[0]*tv[0][q].z + gw[1]*tv[1][q].z + gw[2]*tv[2][q].z + gw[3]*tv[3][q].z;
            float a3 = gw[0]*tv[0][q].w + gw[1]*tv[1][q].w + gw[2]*tv[2][q].w + gw[3]*tv[3][q].w;
            cb[(q*4 + 0)*32] = gm * a0;
            cb[(q*4 + 1)*32] = gm * a1;
            cb[(q*4 + 2)*32] = gm * a2;
            cb[(q*4 + 3)*32] = gm * a3;
        }
    };

    auto gemm = [&](int kk, int buf) {
        const float* wk = wt + (size_t)kk*CIN*OCH + og*4;
        const float* cb = &cols[buf][0];
        for (int g = 0; g < 8; ++g) {                  // c = g*16 + i
            const float* cbg = cb + g*16*32 + ((pg ^ g) << 2);
            const float* wkg = wk + (size_t)g*16*OCH;
            #pragma unroll
            for (int i = 0; i < 16; ++i) {
                float4 wv = *(const float4*)(wkg + (size_t)i*OCH);
                float4 cv = *(const float4*)(cbg + i*32);
                acc[0][0] = fmaf(wv.x, cv.x, acc[0][0]);
                acc[0][1] = fmaf(wv.x, cv.y, acc[0][1]);
                acc[0][2] = fmaf(wv.x, cv.z, acc[0][2]);
                acc[0][3] = fmaf(wv.x, cv.w, acc[0][3]);
                acc[1][0] = fmaf(wv.y, cv.x, acc[1][0]);
                acc[1][1] = fmaf(wv.y, cv.y, acc[1][1]);
                acc[1][2] = fmaf(wv.y, cv.z, acc[1][2]);
                acc[1][3] = fmaf(wv.y, cv.w, acc[1][3]);
                acc[2][0] = fmaf(wv.z, cv.x, acc[2][0]);
                acc[2][1] = fmaf(wv.z, cv.y, acc[2][1]);
                acc[2][2] = fmaf(wv.z, cv.z, acc[2][2]);
                acc[2][3] = fmaf(wv.z, cv.w, acc[2][3]);
                acc[3][0] = fmaf(wv.w, cv.x, acc[3][0]);
                acc[3][1] = fmaf(wv.w, cv.y, acc[3][1]);
                acc[3][2] = fmaf(wv.w, cv.z, acc[3][2]);
                acc[3][3] = fmaf(wv.w, cv.w, acc[3][3]);
            }
        }
    };

    issue(0);
    finish(0);
    __syncthreads();                  // cols[0] ready
    for (int k = 0; k < 9; ++k) {
        int buf = k & 1;
        if (k < 8) issue(k + 1);      // loads in flight during gemm
        gemm(k, buf);
        if (k < 8) finish(buf ^ 1);   // other buffer: no race with gemm reads
        __syncthreads();
    }

    // ---- store NCHW ----
    float* ob = out + (size_t)b*OCH*HW + (size_t)h*WW + w0 + pg*4;
    #pragma unroll
    for (int i = 0; i < 4; ++i) {
        int o = og*4 + i;
        *(float4*)(ob + (size_t)o*HW) = make_float4(acc[i][0], acc[i][1], acc[i][2], acc[i][3]);
    }
}

extern "C" void kernel_launch(void* const* d_in, const int* in_sizes, int n_in,
                              void* d_out, int out_size, void* d_ws, size_t ws_size,
                              hipStream_t stream) {
    const float* x      = (const float*)d_in[0];
    const float* conv_w = (const float*)d_in[1];
    const float* off_w  = (const float*)d_in[2];
    const float* off_b  = (const float*)d_in[3];
    const float* mask_w = (const float*)d_in[4];
    const float* mask_b = (const float*)d_in[5];
    float* out = (float*)d_out;
    float* ws  = (float*)d_ws;

    float* xt  = ws + XT_OFF;
    float* wtp = ws + WT_OFF;
    float* wom = ws + WOM_OFF;
    float* pmm = ws + PMM_OFF;

    k_transpose_x<<<dim3(128, 4, 8), dim3(32, 8), 0, stream>>>(x, xt);
    k_pack_w<<<576, 256, 0, stream>>>(conv_w, off_w, mask_w, wtp, wom);
    k_offmask<<<512, 512, 0, stream>>>(x, wom, off_b, mask_b, pmm);
    k_main<<<1024, 256, 0, stream>>>(xt, wtp, pmm, out);
}

// Round 7
// 330.041 us; speedup vs baseline: 1.3425x; 1.3425x over previous
//
#include <hip/hip_runtime.h>
#include <math.h>

#define BATCH 8
#define CIN 128
#define OCH 128
#define HH 64
#define WW 64
#define HW (HH*WW)
#define NPIX (BATCH*HW)

// ---- workspace layout (float element offsets) ----
#define XT_OFF  0
#define XT_SZ   (BATCH*HW*CIN)            // x transposed to NHWC
#define WT_OFF  (XT_OFF + XT_SZ)
#define WT_SZ   (9*CIN*OCH)               // conv_w as [k][c][o]
#define WOM_OFF (WT_OFF + WT_SZ)
#define WOM_SZ  (9*CIN*28)                // off/mask weights [k][c][28]
#define PMM_OFF (WOM_OFF + WOM_SZ)
#define PMM_SZ  (NPIX*32)                 // per-pixel py[9],px[9],m[9]

// ============ kernel 1a: x NCHW -> NHWC ============
__global__ __launch_bounds__(256) void k_transpose_x(const float* __restrict__ x,
                                                     float* __restrict__ xt) {
    __shared__ float tile[32][33];
    int b   = blockIdx.z;
    int hw0 = blockIdx.x * 32;
    int c0  = blockIdx.y * 32;
    int tx = threadIdx.x, ty = threadIdx.y;
    const float* xin = x  + (size_t)b*CIN*HW;
    float*       xo  = xt + (size_t)b*HW*CIN;
    #pragma unroll
    for (int r = 0; r < 32; r += 8)
        tile[ty + r][tx] = xin[(size_t)(c0 + ty + r)*HW + hw0 + tx];
    __syncthreads();
    #pragma unroll
    for (int r = 0; r < 32; r += 8)
        xo[(size_t)(hw0 + ty + r)*CIN + c0 + tx] = tile[tx][ty + r];
}

// ============ kernel 1b: pack weights ============
__global__ __launch_bounds__(256) void k_pack_w(const float* __restrict__ conv_w,
                                                const float* __restrict__ off_w,
                                                const float* __restrict__ mask_w,
                                                float* __restrict__ wt,
                                                float* __restrict__ wom) {
    int idx = blockIdx.x * 256 + threadIdx.x;
    if (idx < 9*CIN*OCH) {
        int k = idx / (CIN*OCH);
        int rc = idx - k*(CIN*OCH);
        int c = rc / OCH;
        int o = rc - c*OCH;
        wt[idx] = conv_w[(size_t)(o*CIN + c)*9 + k];
    }
    if (idx < 9*CIN*28) {
        int k = idx / (CIN*28);
        int r2 = idx - k*(CIN*28);
        int c = r2 / 28;
        int j = r2 - c*28;
        float v = 0.f;
        if (j < 18)      v = off_w [(size_t)(j*CIN + c)*9 + k];
        else if (j < 27) v = mask_w[(size_t)((j-18)*CIN + c)*9 + k];
        wom[idx] = v;
    }
}

// ============ kernel 2: offset+mask conv -> pmm ============
// block = 512 threads = 64 px x 8 c-groups of 16ch; grid = B*H = 512.
// XCD swizzle: 512 = 8*64 -> each XCD owns one batch image (L2-resident).
__global__ __launch_bounds__(512) void k_offmask(const float* __restrict__ x,
                                                 const float* __restrict__ wom,
                                                 const float* __restrict__ off_b,
                                                 const float* __restrict__ mask_b,
                                                 float* __restrict__ pmm) {
    int bid = blockIdx.x;
    int blk = (bid & 7) * 64 + (bid >> 3);             // bijective, 512%8==0
    int b = blk >> 6;
    int h = blk & 63;
    int t = threadIdx.x;
    int p = t & 63;                                    // pixel (abs w)
    int cg = __builtin_amdgcn_readfirstlane(t >> 6);   // 0..7, wave-uniform

    float acc[27];
    #pragma unroll
    for (int j = 0; j < 27; ++j) acc[j] = 0.f;

    const float* xb = x + (size_t)b*CIN*HW + (size_t)(cg*16)*HW;
    const float* wbase = wom + (size_t)(cg*16)*28;
    for (int k = 0; k < 9; ++k) {
        int ky = k / 3, kx = k - ky*3;
        int y = h + ky - 1;
        if ((unsigned)y >= HH) continue;
        int xx = p + kx - 1;
        bool vx = (unsigned)xx < WW;
        const float* xp = xb + y*WW + xx;
        const float* wp = wbase + (size_t)k*CIN*28;    // wave-uniform -> s_load
        #pragma unroll
        for (int i = 0; i < 16; ++i) {
            float xv = vx ? xp[(size_t)i*HW] : 0.f;
            #pragma unroll
            for (int j = 0; j < 27; ++j)
                acc[j] = fmaf(xv, wp[i*28 + j], acc[j]);
        }
    }

    __shared__ float red[8][64][33];                   // +1 pad
    #pragma unroll
    for (int j = 0; j < 27; ++j) red[cg][p][j] = acc[j];
    __syncthreads();

    int rowpix = (b*HH + h)*WW;
    for (int idx = t; idx < 64*32; idx += 512) {
        int pp = idx >> 5, j = idx & 31;
        if (j >= 27) continue;
        float s = 0.f;
        #pragma unroll
        for (int g = 0; g < 8; ++g) s += red[g][pp][j];
        float outv; int slot;
        if (j < 18) {
            int kk = j >> 1;
            s += off_b[j];
            int kyy = kk / 3;
            if ((j & 1) == 0) { outv = (float)(h - 1 + kyy) + s;            slot = kk;     }
            else              { outv = (float)(pp - 1 + (kk - kyy*3)) + s;  slot = 9 + kk; }
        } else {
            s += mask_b[j - 18];
            outv = 1.f / (1.f + expf(-s));
            slot = j;
        }
        pmm[(size_t)(rowpix + pp)*32 + slot] = outv;
    }
}

// ============ kernel 3: gather + main GEMM ============
// block = 256 threads (4 waves), 32 px; grid 1024 = 4 blocks/CU (16 waves/CU).
// XCD swizzle (1024 = 8*128): each XCD owns one batch image (2.1 MiB xt slab
// L2-resident across all 9 k-passes).
// Gather is FUSED (loads feed FMAs directly, ~8 float4 live at a time):
// round 4 proved a 64-VGPR prefetch buffer under the 128-VGPR cap spills to
// scratch (WRITE_SIZE 16->535 MB). No barrier between gemm(k) and gather(k+1)
// -> compiler may still hoist gather loads into the gemm tail for free overlap.
__global__ __launch_bounds__(256, 4) void k_main(const float* __restrict__ xt,
                                                 const float* __restrict__ wt,
                                                 const float* __restrict__ pmm,
                                                 float* __restrict__ out) {
    __shared__ float cols[2][CIN*32];                  // 32 KB

    int bid = blockIdx.x;
    int blk = (bid & 7) * 128 + (bid >> 3);            // bijective, 1024%8==0
    int b = blk >> 7;
    int r = blk & 127;
    int h = r >> 1;
    int w0 = (r & 1) << 5;
    int t = threadIdx.x;

    int og = t >> 3, pg = t & 7;      // GEMM roles: o=og*4, p=pg*4
    int gpx = t >> 3, gcg = t & 7;    // gather roles: pixel, 16-ch group

    int rowpix = (b*HH + h)*WW + w0;
    const float* xb = xt + (size_t)b*HW*CIN;
    const float* pmmp = pmm + (size_t)(rowpix + gpx)*32;

    // swizzled cols layout: (c,p) at dword c*32 + (((p>>2)^(c>>4))<<2) + (p&3)
    int wbase = gcg*16*32 + (((gpx >> 2) ^ gcg) << 2) + (gpx & 3);

    float acc[4][4];
    #pragma unroll
    for (int i = 0; i < 4; ++i)
        #pragma unroll
        for (int j = 0; j < 4; ++j) acc[i][j] = 0.f;

    auto gather = [&](int kk, int buf) {
        float py = pmmp[kk];
        float qx = pmmp[9 + kk];
        float m  = pmmp[18 + kk];
        float fy = floorf(py), fx = floorf(qx);
        float wy = py - fy, wx = qx - fx;
        int iy = (int)fy, ix = (int)fx;
        float a[16];
        #pragma unroll
        for (int i = 0; i < 16; ++i) a[i] = 0.f;
        #pragma unroll
        for (int tp = 0; tp < 4; ++tp) {
            int yy = iy + (tp >> 1), xv = ix + (tp & 1);
            bool valid = ((unsigned)yy < HH) && ((unsigned)xv < WW);
            float tw = ((tp >> 1) ? wy : 1.f - wy) * ((tp & 1) ? wx : 1.f - wx);
            tw = valid ? tw : 0.f;                     // branchless OOB: w=0
            int yc = min(max(yy, 0), HH - 1);
            int xc = min(max(xv, 0), WW - 1);
            const float* src = xb + (size_t)(yc*WW + xc)*CIN + gcg*16;
            #pragma unroll
            for (int q = 0; q < 4; ++q) {
                float4 v = *(const float4*)(src + q*4);
                a[4*q+0] = fmaf(tw, v.x, a[4*q+0]);
                a[4*q+1] = fmaf(tw, v.y, a[4*q+1]);
                a[4*q+2] = fmaf(tw, v.z, a[4*q+2]);
                a[4*q+3] = fmaf(tw, v.w, a[4*q+3]);
            }
        }
        float* cb = &cols[buf][0] + wbase;
        #pragma unroll
        for (int i = 0; i < 16; ++i) cb[i*32] = m * a[i];
    };

    auto gemm = [&](int kk, int buf) {
        const float* wk = wt + (size_t)kk*CIN*OCH + og*4;
        const float* cb = &cols[buf][0];
        for (int g = 0; g < 8; ++g) {                  // c = g*16 + i
            const float* cbg = cb + g*16*32 + ((pg ^ g) << 2);
            const float* wkg = wk + (size_t)g*16*OCH;
            #pragma unroll
            for (int i = 0; i < 16; ++i) {
                float4 wv = *(const float4*)(wkg + (size_t)i*OCH);
                float4 cv = *(const float4*)(cbg + i*32);
                acc[0][0] = fmaf(wv.x, cv.x, acc[0][0]);
                acc[0][1] = fmaf(wv.x, cv.y, acc[0][1]);
                acc[0][2] = fmaf(wv.x, cv.z, acc[0][2]);
                acc[0][3] = fmaf(wv.x, cv.w, acc[0][3]);
                acc[1][0] = fmaf(wv.y, cv.x, acc[1][0]);
                acc[1][1] = fmaf(wv.y, cv.y, acc[1][1]);
                acc[1][2] = fmaf(wv.y, cv.z, acc[1][2]);
                acc[1][3] = fmaf(wv.y, cv.w, acc[1][3]);
                acc[2][0] = fmaf(wv.z, cv.x, acc[2][0]);
                acc[2][1] = fmaf(wv.z, cv.y, acc[2][1]);
                acc[2][2] = fmaf(wv.z, cv.z, acc[2][2]);
                acc[2][3] = fmaf(wv.z, cv.w, acc[2][3]);
                acc[3][0] = fmaf(wv.w, cv.x, acc[3][0]);
                acc[3][1] = fmaf(wv.w, cv.y, acc[3][1]);
                acc[3][2] = fmaf(wv.w, cv.z, acc[3][2]);
                acc[3][3] = fmaf(wv.w, cv.w, acc[3][3]);
            }
        }
    };

    gather(0, 0);
    __syncthreads();
    for (int k = 0; k < 9; ++k) {
        int buf = k & 1;
        gemm(k, buf);
        if (k < 8) gather(k + 1, buf ^ 1);   // other buffer: no race
        __syncthreads();
    }

    // ---- store NCHW ----
    float* ob = out + (size_t)b*OCH*HW + (size_t)h*WW + w0 + pg*4;
    #pragma unroll
    for (int i = 0; i < 4; ++i) {
        int o = og*4 + i;
        *(float4*)(ob + (size_t)o*HW) = make_float4(acc[i][0], acc[i][1], acc[i][2], acc[i][3]);
    }
}

extern "C" void kernel_launch(void* const* d_in, const int* in_sizes, int n_in,
                              void* d_out, int out_size, void* d_ws, size_t ws_size,
                              hipStream_t stream) {
    const float* x      = (const float*)d_in[0];
    const float* conv_w = (const float*)d_in[1];
    const float* off_w  = (const float*)d_in[2];
    const float* off_b  = (const float*)d_in[3];
    const float* mask_w = (const float*)d_in[4];
    const float* mask_b = (const float*)d_in[5];
    float* out = (float*)d_out;
    float* ws  = (float*)d_ws;

    float* xt  = ws + XT_OFF;
    float* wtp = ws + WT_OFF;
    float* wom = ws + WOM_OFF;
    float* pmm = ws + PMM_OFF;

    k_transpose_x<<<dim3(128, 4, 8), dim3(32, 8), 0, stream>>>(x, xt);
    k_pack_w<<<576, 256, 0, stream>>>(conv_w, off_w, mask_w, wtp, wom);
    k_offmask<<<512, 512, 0, stream>>>(x, wom, off_b, mask_b, pmm);
    k_main<<<1024, 256, 0, stream>>>(xt, wtp, pmm, out);
}

// Round 12
// 219.674 us; speedup vs baseline: 2.0170x; 1.5024x over previous
//
#include <hip/hip_runtime.h>
#include <math.h>

#define BATCH 8
#define CIN 128
#define OCH 128
#define HH 64
#define WW 64
#define HW (HH*WW)
#define NPIX (BATCH*HW)

typedef __attribute__((ext_vector_type(8))) short short8;
typedef __attribute__((ext_vector_type(4))) float f32x4;

// bf16 split helpers (RNE, branchless, no header dependence)
static __device__ __forceinline__ short f2bf(float f) {
    unsigned u = __builtin_bit_cast(unsigned, f);
    unsigned r = u + 0x7fffu + ((u >> 16) & 1u);
    return (short)(r >> 16);
}
static __device__ __forceinline__ float bf2f(short s) {
    unsigned u = ((unsigned)(unsigned short)s) << 16;
    return __builtin_bit_cast(float, u);
}

// ---- workspace layout (float element offsets) ----
#define XT_OFF   0
#define XT_SZ    (BATCH*HW*CIN)              // x transposed to NHWC
#define WTFH_OFF (XT_OFF + XT_SZ)            // conv_w hi-split, MFMA fragment order
#define WTF_SZF  (9*8*4*64*8/2)              // 147456 shorts = 73728 floats
#define WTFL_OFF (WTFH_OFF + WTF_SZF)        // lo-split
#define WOM_OFF  (WTFL_OFF + WTF_SZF)
#define WOM_SZ   (9*CIN*28)                  // off/mask weights [k][c][28]
#define PMM_OFF  (WOM_OFF + WOM_SZ)
#define PMM_SZ   (NPIX*32)                   // per-pixel py[9],px[9],m[9]

// ============ kernel 1a: x NCHW -> NHWC ============
__global__ __launch_bounds__(256) void k_transpose_x(const float* __restrict__ x,
                                                     float* __restrict__ xt) {
    __shared__ float tile[32][33];
    int b   = blockIdx.z;
    int hw0 = blockIdx.x * 32;
    int c0  = blockIdx.y * 32;
    int tx = threadIdx.x, ty = threadIdx.y;
    const float* xin = x  + (size_t)b*CIN*HW;
    float*       xo  = xt + (size_t)b*HW*CIN;
    #pragma unroll
    for (int r = 0; r < 32; r += 8)
        tile[ty + r][tx] = xin[(size_t)(c0 + ty + r)*HW + hw0 + tx];
    __syncthreads();
    #pragma unroll
    for (int r = 0; r < 32; r += 8)
        xo[(size_t)(hw0 + ty + r)*CIN + c0 + tx] = tile[tx][ty + r];
}

// ============ kernel 1b: pack weights ============
// wtf_{hi,lo}[(((k*8+mt)*4+kt)*64+l)*8+j] = split(conv_w[o][c][k]),
//   o = mt*16 + (l&15), c = kt*32 + (l>>4)*8 + j   (MFMA A-fragment order)
// wom[k][c][j] unchanged.
__global__ __launch_bounds__(256) void k_pack_w(const float* __restrict__ conv_w,
                                                const float* __restrict__ off_w,
                                                const float* __restrict__ mask_w,
                                                short* __restrict__ wtfh,
                                                short* __restrict__ wtfl,
                                                float* __restrict__ wom) {
    int idx = blockIdx.x * 256 + threadIdx.x;   // grid covers 147456 exactly
    {
        int j  = idx & 7;
        int l  = (idx >> 3) & 63;
        int kt = (idx >> 9) & 3;
        int mt = (idx >> 11) & 7;
        int k  = idx >> 14;
        int o = mt*16 + (l & 15);
        int c = kt*32 + ((l >> 4) << 3) + j;
        float v = conv_w[(size_t)(o*CIN + c)*9 + k];
        short hi = f2bf(v);
        wtfh[idx] = hi;
        wtfl[idx] = f2bf(v - bf2f(hi));
    }
    if (idx < 9*CIN*28) {
        int k = idx / (CIN*28);
        int r2 = idx - k*(CIN*28);
        int c = r2 / 28;
        int j = r2 - c*28;
        float v = 0.f;
        if (j < 18)      v = off_w [(size_t)(j*CIN + c)*9 + k];
        else if (j < 27) v = mask_w[(size_t)((j-18)*CIN + c)*9 + k];
        wom[idx] = v;
    }
}

// ============ kernel 2: offset+mask conv -> pmm ============  (unchanged)
__global__ __launch_bounds__(512) void k_offmask(const float* __restrict__ x,
                                                 const float* __restrict__ wom,
                                                 const float* __restrict__ off_b,
                                                 const float* __restrict__ mask_b,
                                                 float* __restrict__ pmm) {
    int bid = blockIdx.x;
    int blk = (bid & 7) * 64 + (bid >> 3);             // bijective, 512%8==0
    int b = blk >> 6;
    int h = blk & 63;
    int t = threadIdx.x;
    int p = t & 63;
    int cg = __builtin_amdgcn_readfirstlane(t >> 6);

    float acc[27];
    #pragma unroll
    for (int j = 0; j < 27; ++j) acc[j] = 0.f;

    const float* xb = x + (size_t)b*CIN*HW + (size_t)(cg*16)*HW;
    const float* wbase = wom + (size_t)(cg*16)*28;
    for (int k = 0; k < 9; ++k) {
        int ky = k / 3, kx = k - ky*3;
        int y = h + ky - 1;
        if ((unsigned)y >= HH) continue;
        int xx = p + kx - 1;
        bool vx = (unsigned)xx < WW;
        const float* xp = xb + y*WW + xx;
        const float* wp = wbase + (size_t)k*CIN*28;
        #pragma unroll
        for (int i = 0; i < 16; ++i) {
            float xv = vx ? xp[(size_t)i*HW] : 0.f;
            #pragma unroll
            for (int j = 0; j < 27; ++j)
                acc[j] = fmaf(xv, wp[i*28 + j], acc[j]);
        }
    }

    __shared__ float red[8][64][33];
    #pragma unroll
    for (int j = 0; j < 27; ++j) red[cg][p][j] = acc[j];
    __syncthreads();

    int rowpix = (b*HH + h)*WW;
    for (int idx = t; idx < 64*32; idx += 512) {
        int pp = idx >> 5, j = idx & 31;
        if (j >= 27) continue;
        float s = 0.f;
        #pragma unroll
        for (int g = 0; g < 8; ++g) s += red[g][pp][j];
        float outv; int slot;
        if (j < 18) {
            int kk = j >> 1;
            s += off_b[j];
            int kyy = kk / 3;
            if ((j & 1) == 0) { outv = (float)(h - 1 + kyy) + s;            slot = kk;     }
            else              { outv = (float)(pp - 1 + (kk - kyy*3)) + s;  slot = 9 + kk; }
        } else {
            s += mask_b[j - 18];
            outv = 1.f / (1.f + expf(-s));
            slot = j;
        }
        pmm[(size_t)(rowpix + pp)*32 + slot] = outv;
    }
}

// ============ kernel 3: gather + split-bf16 MFMA GEMM ============
// block = 256 threads (4 waves), out tile 128o x 32p; grid 1024, XCD-swizzled.
// Wave w owns o-range w*32 (2 M-tiles). Per k: gather->bf16 hi/lo cols in LDS
// ([p][c] bf16, 16B-block XOR swizzle blk^(p&7)), then 48 mfma_16x16x32_bf16
// per wave (2M x 2N x 4K x 3 split-products; lo*lo dropped, ~2^-17 rel err).
// A-frags streamed from global in fragment order (coalesced short8).
// Layouts per guide §3 (m89-verified): A row=l&15, k=(l>>4)*8+j;
// B col=l&15, same k; D col=l&15, row=(l>>4)*4+reg.
__global__ __launch_bounds__(256, 4) void k_main(const float* __restrict__ xt,
                                                 const short* __restrict__ wtfh,
                                                 const short* __restrict__ wtfl,
                                                 const float* __restrict__ pmm,
                                                 float* __restrict__ out) {
    __shared__ short8 cols8[2][2][32*16];              // [buf][hi/lo][p*16+blk] 32KB

    int bid = blockIdx.x;
    int blk = (bid & 7) * 128 + (bid >> 3);            // bijective, 1024%8==0
    int b = blk >> 7;
    int r = blk & 127;
    int h = r >> 1;
    int w0 = (r & 1) << 5;
    int t = threadIdx.x;

    int gp = t >> 3, gcg = t & 7;                      // gather: pixel, 16-ch grp
    int lane = t & 63, wave = t >> 6;                  // mfma roles

    int rowpix = (b*HH + h)*WW + w0;
    const float* xb = xt + (size_t)b*HW*CIN;
    const float* pmmp = pmm + (size_t)(rowpix + gp)*32;

    f32x4 zero4 = {0.f, 0.f, 0.f, 0.f};
    f32x4 acc[2][2] = {{zero4, zero4}, {zero4, zero4}};

    auto gather = [&](int kk, int buf) {
        float py = pmmp[kk];
        float qx = pmmp[9 + kk];
        float m  = pmmp[18 + kk];
        float fy = floorf(py), fx = floorf(qx);
        float wy = py - fy, wx = qx - fx;
        int iy = (int)fy, ix = (int)fx;
        float a[16];
        #pragma unroll
        for (int i = 0; i < 16; ++i) a[i] = 0.f;
        #pragma unroll
        for (int tp = 0; tp < 4; ++tp) {
            int yy = iy + (tp >> 1), xv = ix + (tp & 1);
            bool valid = ((unsigned)yy < HH) && ((unsigned)xv < WW);
            float tw = ((tp >> 1) ? wy : 1.f - wy) * ((tp & 1) ? wx : 1.f - wx);
            tw = valid ? tw : 0.f;                     // branchless OOB: w=0
            int yc = min(max(yy, 0), HH - 1);
            int xc = min(max(xv, 0), WW - 1);
            const float* src = xb + (size_t)(yc*WW + xc)*CIN + gcg*16;
            #pragma unroll
            for (int q = 0; q < 4; ++q) {
                float4 v = *(const float4*)(src + q*4);
                a[4*q+0] = fmaf(tw, v.x, a[4*q+0]);
                a[4*q+1] = fmaf(tw, v.y, a[4*q+1]);
                a[4*q+2] = fmaf(tw, v.z, a[4*q+2]);
                a[4*q+3] = fmaf(tw, v.w, a[4*q+3]);
            }
        }
        int p7 = gp & 7;
        #pragma unroll
        for (int bb = 0; bb < 2; ++bb) {
            short8 vh, vl;
            #pragma unroll
            for (int j = 0; j < 8; ++j) {
                float v = m * a[bb*8 + j];
                short hi = f2bf(v);
                vh[j] = hi;
                vl[j] = f2bf(v - bf2f(hi));
            }
            int bi = (2*gcg + bb) ^ p7;                // 16B-block XOR swizzle
            cols8[buf][0][gp*16 + bi] = vh;
            cols8[buf][1][gp*16 + bi] = vl;
        }
    };

    auto mma = [&](int kk, int buf) {
        #pragma unroll
        for (int kt = 0; kt < 4; ++kt) {
            short8 bh[2], bl[2];
            #pragma unroll
            for (int nt = 0; nt < 2; ++nt) {
                int p = nt*16 + (lane & 15);
                int bi = (kt*4 + (lane >> 4)) ^ (p & 7);
                bh[nt] = cols8[buf][0][p*16 + bi];
                bl[nt] = cols8[buf][1][p*16 + bi];
            }
            short8 ah[2], al[2];
            #pragma unroll
            for (int mtl = 0; mtl < 2; ++mtl) {
                int mt = wave*2 + mtl;
                size_t off = ((((size_t)kk*8 + mt)*4 + kt)*64 + lane)*8;
                ah[mtl] = *(const short8*)(wtfh + off);
                al[mtl] = *(const short8*)(wtfl + off);
            }
            #pragma unroll
            for (int mtl = 0; mtl < 2; ++mtl)
                #pragma unroll
                for (int nt = 0; nt < 2; ++nt) {
                    acc[mtl][nt] = __builtin_amdgcn_mfma_f32_16x16x32_bf16(ah[mtl], bh[nt], acc[mtl][nt], 0, 0, 0);
                    acc[mtl][nt] = __builtin_amdgcn_mfma_f32_16x16x32_bf16(al[mtl], bh[nt], acc[mtl][nt], 0, 0, 0);
                    acc[mtl][nt] = __builtin_amdgcn_mfma_f32_16x16x32_bf16(ah[mtl], bl[nt], acc[mtl][nt], 0, 0, 0);
                }
        }
    };

    gather(0, 0);
    __syncthreads();
    for (int k = 0; k < 9; ++k) {
        int buf = k & 1;
        mma(k, buf);
        if (k < 8) gather(k + 1, buf ^ 1);   // other buffer: no race
        __syncthreads();
    }

    // ---- store NCHW (D layout: col=lane&15 -> p, row=(lane>>4)*4+reg -> o) ----
    float* ob = out + (size_t)b*OCH*HW + (size_t)h*WW;
    #pragma unroll
    for (int mtl = 0; mtl < 2; ++mtl)
        #pragma unroll
        for (int nt = 0; nt < 2; ++nt) {
            int o = wave*32 + mtl*16 + (lane >> 4)*4;
            int p = w0 + nt*16 + (lane & 15);
            #pragma unroll
            for (int reg = 0; reg < 4; ++reg)
                ob[(size_t)(o + reg)*HW + p] = acc[mtl][nt][reg];
        }
}

extern "C" void kernel_launch(void* const* d_in, const int* in_sizes, int n_in,
                              void* d_out, int out_size, void* d_ws, size_t ws_size,
                              hipStream_t stream) {
    const float* x      = (const float*)d_in[0];
    const float* conv_w = (const float*)d_in[1];
    const float* off_w  = (const float*)d_in[2];
    const float* off_b  = (const float*)d_in[3];
    const float* mask_w = (const float*)d_in[4];
    const float* mask_b = (const float*)d_in[5];
    float* out = (float*)d_out;
    float* ws  = (float*)d_ws;

    float* xt   = ws + XT_OFF;
    short* wtfh = (short*)(ws + WTFH_OFF);
    short* wtfl = (short*)(ws + WTFL_OFF);
    float* wom  = ws + WOM_OFF;
    float* pmm  = ws + PMM_OFF;

    k_transpose_x<<<dim3(128, 4, 8), dim3(32, 8), 0, stream>>>(x, xt);
    k_pack_w<<<576, 256, 0, stream>>>(conv_w, off_w, mask_w, wtfh, wtfl, wom);
    k_offmask<<<512, 512, 0, stream>>>(x, wom, off_b, mask_b, pmm);
    k_main<<<1024, 256, 0, stream>>>(xt, wtfh, wtfl, pmm, out);
}